// Round 6
// baseline (213.459 us; speedup 1.0000x reference)
//
#include <hip/hip_runtime.h>
#include <cstdint>
#include <cstddef>

// ---------------- problem constants ----------------
#define Bb   8
#define Nn   1024
#define Ccn  768
#define Hh   12
#define DHn  64
#define Mrows (Bb * Nn)   // 8192
#define N3C  (3 * Ccn)    // 2304
#define BHn  (Bb * Hh)    // 96

typedef __attribute__((ext_vector_type(8))) short bf16x8;   // 8 bf16 (4 VGPRs)
typedef __attribute__((ext_vector_type(4))) float f32x4;

static __device__ __forceinline__ unsigned short f2bf(float f) {
    unsigned int u = __builtin_bit_cast(unsigned int, f);
    return (unsigned short)((u + 0x7FFFu + ((u >> 16) & 1u)) >> 16);  // RNE
}
static __device__ __forceinline__ float bf2f(unsigned short s) {
    unsigned int u = ((unsigned int)s) << 16;
    return __builtin_bit_cast(float, u);
}
// pack two f32 -> two bf16 (round half-up; inputs are finite non-negative p's)
static __device__ __forceinline__ unsigned pack2bf(float a, float b) {
    unsigned ua = __builtin_bit_cast(unsigned, a) + 0x8000u;
    unsigned ub = __builtin_bit_cast(unsigned, b) + 0x8000u;
    return (ua >> 16) | (ub & 0xFFFF0000u);
}
// async global->LDS, 16B per lane; LDS dest must be (wave-uniform base + lane*16)
static __device__ __forceinline__ void glds16(const void* g, void* l) {
    __builtin_amdgcn_global_load_lds((const __attribute__((address_space(1))) void*)g,
                                     (__attribute__((address_space(3))) void*)l,
                                     16, 0, 0);
}

// ---------------- prep kernels ----------------
// x fp32 -> bf16 (vectorized) + mask int -> additive bias (0 / -1e9), fused
__global__ void convert_x_mask_kernel(const float* __restrict__ x,
                                      unsigned short* __restrict__ xb,
                                      const int* __restrict__ mask,
                                      float* __restrict__ maskneg, int n8) {
    int i = blockIdx.x * blockDim.x + threadIdx.x;
    if (i < Mrows) maskneg[i] = (mask[i] != 0) ? -1.0e9f : 0.0f;
    if (i >= n8) return;
    const f32x4* xp = (const f32x4*)x;
    f32x4 a = xp[2 * i], b = xp[2 * i + 1];
    bf16x8 v;
#pragma unroll
    for (int j = 0; j < 4; ++j) {
        v[j]     = (short)f2bf(a[j]);
        v[4 + j] = (short)f2bf(b[j]);
    }
    ((bf16x8*)xb)[i] = v;
}

// both weight transposes in one launch: blockIdx.x<72 -> w_qkv, else w_proj
__global__ void transpose_w2_kernel(const float* __restrict__ Wqkv,
                                    unsigned short* __restrict__ WqkvT,
                                    const float* __restrict__ Wproj,
                                    unsigned short* __restrict__ WprojT) {
    __shared__ float tile[32][33];
    int xb = blockIdx.x;
    const float* W; unsigned short* WT; int C;
    if (xb < 72) { W = Wqkv;  WT = WqkvT;  C = N3C; }
    else         { W = Wproj; WT = WprojT; C = Ccn; xb -= 72; }
    const int R = Ccn;
    const int c0 = xb * 32, r0 = blockIdx.y * 32;
    const int tx = threadIdx.x, ty = threadIdx.y;
#pragma unroll
    for (int i = 0; i < 4; ++i)
        tile[ty + i * 8][tx] = W[(size_t)(r0 + ty + i * 8) * C + c0 + tx];
    __syncthreads();
#pragma unroll
    for (int i = 0; i < 4; ++i)
        WT[(size_t)(c0 + ty + i * 8) * R + r0 + tx] = f2bf(tile[tx][ty + i * 8]);
}

// per (b,h): V (1024 x 64) bf16 -> VT (64 x 1024) bf16
__global__ void transpose_v_kernel(const unsigned short* __restrict__ vb,
                                   unsigned short* __restrict__ vtb) {
    __shared__ unsigned short tile[32][34];
    const int bh = blockIdx.z;
    const int d0 = blockIdx.x * 32, n0 = blockIdx.y * 32;
    const int tx = threadIdx.x, ty = threadIdx.y;
    const unsigned short* src = vb + (size_t)bh * Nn * DHn;
    unsigned short* dst = vtb + (size_t)bh * DHn * Nn;
#pragma unroll
    for (int i = 0; i < 4; ++i)
        tile[ty + i * 8][tx] = src[(size_t)(n0 + ty + i * 8) * DHn + d0 + tx];
    __syncthreads();
#pragma unroll
    for (int i = 0; i < 4; ++i)
        dst[(size_t)(d0 + ty + i * 8) * Nn + n0 + tx] = tile[tx][ty + i * 8];
}

// ---------------- m97-style bf16 GEMM, 128x128 tile, BK=32, swizzled LDS ----
__global__ __launch_bounds__(256) void gemm_qkv_kernel(
    const unsigned short* __restrict__ A,
    const unsigned short* __restrict__ BT,
    unsigned short* __restrict__ qkvb) {
    constexpr int K = Ccn;
    const int bm = blockIdx.x, bn = blockIdx.y;
    const int t = threadIdx.x, wv = t >> 6, l = t & 63;
    const int fr = l & 15, quad = l >> 4;
    const int wm = (wv >> 1) * 64, wn = (wv & 1) * 64;
    __shared__ __align__(16) unsigned short As[128 * 32];
    __shared__ __align__(16) unsigned short Bs[128 * 32];
    const f32x4 zero = {0.f, 0.f, 0.f, 0.f};
    f32x4 acc[4][4];
#pragma unroll
    for (int i = 0; i < 4; ++i)
#pragma unroll
        for (int j = 0; j < 4; ++j) acc[i][j] = zero;

    const int srow = wv * 16 + (l >> 2);                        // 0..63
    const int scol_dst = (l & 3) * 8;                           // linear dest chunk
    const int scol_src = (((l & 3) ^ ((srow >> 1) & 3)) << 3);  // swizzled source chunk
    const unsigned short* Ag = A + (size_t)(bm * 128 + srow) * K + scol_src;
    const unsigned short* Bg = BT + (size_t)(bn * 128 + srow) * K + scol_src;
    unsigned short* Al = &As[srow * 32 + scol_dst];
    unsigned short* Bl = &Bs[srow * 32 + scol_dst];
    const int rsw = ((fr >> 1) & 3);                            // read-side swizzle

    for (int k0 = 0; k0 < K; k0 += 32) {
        glds16(Ag, Al);
        glds16(Ag + (size_t)64 * K, Al + 64 * 32);
        glds16(Bg, Bl);
        glds16(Bg + (size_t)64 * K, Bl + 64 * 32);
        Ag += 32; Bg += 32;
        __syncthreads();
        bf16x8 af[4], bfv[4];
#pragma unroll
        for (int i = 0; i < 4; ++i)
            af[i] = *(const bf16x8*)&As[(wm + i * 16 + fr) * 32 + ((quad ^ rsw) << 3)];
#pragma unroll
        for (int i = 0; i < 4; ++i)
            bfv[i] = *(const bf16x8*)&Bs[(wn + i * 16 + fr) * 32 + ((quad ^ rsw) << 3)];
#pragma unroll
        for (int i = 0; i < 4; ++i)
#pragma unroll
            for (int j = 0; j < 4; ++j)
                acc[i][j] = __builtin_amdgcn_mfma_f32_16x16x32_bf16(af[i], bfv[j], acc[i][j], 0, 0, 0);
        __syncthreads();
    }
    // epilogue: C row = bm*128+wm+i*16+quad*4+r ; col = bn*128+wn+j*16+fr -> (s,h,d)
#pragma unroll
    for (int j = 0; j < 4; ++j) {
        int col = bn * 128 + wn + j * 16 + fr;
        int s = col / Ccn;
        int rem = col - s * Ccn;
        int hh = rem >> 6, d = rem & 63;
#pragma unroll
        for (int i = 0; i < 4; ++i) {
#pragma unroll
            for (int r = 0; r < 4; ++r) {
                int row = bm * 128 + wm + i * 16 + quad * 4 + r;
                int b = row >> 10, nq = row & 1023;
                qkvb[((((size_t)s * Bb + b) * Hh + hh) * Nn + nq) * DHn + d] = f2bf(acc[i][j][r]);
            }
        }
    }
}

// 128x64 tile (N=768 -> 12 col-blocks, grid 768 = 3 blocks/CU balance)
__global__ __launch_bounds__(256) void gemm_proj_kernel(
    const unsigned short* __restrict__ A,   // attnb 8192 x 768
    const unsigned short* __restrict__ BT,  // wprojT 768 x 768
    const float* __restrict__ bias,
    float* __restrict__ out) {
    constexpr int K = Ccn;
    const int bm = blockIdx.x, bn = blockIdx.y;
    const int t = threadIdx.x, wv = t >> 6, l = t & 63;
    const int fr = l & 15, quad = l >> 4;
    const int wm = (wv >> 1) * 64, wn = (wv & 1) * 32;
    __shared__ __align__(16) unsigned short As[128 * 32];
    __shared__ __align__(16) unsigned short Bs[64 * 32];
    const f32x4 zero = {0.f, 0.f, 0.f, 0.f};
    f32x4 acc[4][2];
#pragma unroll
    for (int i = 0; i < 4; ++i)
#pragma unroll
        for (int j = 0; j < 2; ++j) acc[i][j] = zero;

    const int srow = wv * 16 + (l >> 2);
    const int scol_dst = (l & 3) * 8;
    const int scol_src = (((l & 3) ^ ((srow >> 1) & 3)) << 3);
    const unsigned short* Ag = A + (size_t)(bm * 128 + srow) * K + scol_src;
    unsigned short* Al = &As[srow * 32 + scol_dst];
    const int rB = t >> 2, cB = t & 3;                         // B tile: 64 rows x 4 chunks
    const int bsrc = ((cB ^ ((rB >> 1) & 3)) << 3);
    const unsigned short* Bg = BT + (size_t)(bn * 64 + rB) * K + bsrc;
    unsigned short* Bl = &Bs[rB * 32 + cB * 8];
    const int rsw = ((fr >> 1) & 3);

    for (int k0 = 0; k0 < K; k0 += 32) {
        glds16(Ag, Al);
        glds16(Ag + (size_t)64 * K, Al + 64 * 32);
        glds16(Bg, Bl);
        Ag += 32; Bg += 32;
        __syncthreads();
        bf16x8 af[4], bfv[2];
#pragma unroll
        for (int i = 0; i < 4; ++i)
            af[i] = *(const bf16x8*)&As[(wm + i * 16 + fr) * 32 + ((quad ^ rsw) << 3)];
#pragma unroll
        for (int j = 0; j < 2; ++j)
            bfv[j] = *(const bf16x8*)&Bs[(wn + j * 16 + fr) * 32 + ((quad ^ rsw) << 3)];
#pragma unroll
        for (int i = 0; i < 4; ++i)
#pragma unroll
            for (int j = 0; j < 2; ++j)
                acc[i][j] = __builtin_amdgcn_mfma_f32_16x16x32_bf16(af[i], bfv[j], acc[i][j], 0, 0, 0);
        __syncthreads();
    }
#pragma unroll
    for (int j = 0; j < 2; ++j) {
        int col = bn * 64 + wn + j * 16 + fr;
        float bv = bias[col];
#pragma unroll
        for (int i = 0; i < 4; ++i) {
#pragma unroll
            for (int r = 0; r < 4; ++r) {
                int row = bm * 128 + wm + i * 16 + quad * 4 + r;
                out[(size_t)row * Ccn + col] = acc[i][j][r] + bv;
            }
        }
    }
}

// ---------------- fused flash attention ---------------------------------------
// S^T formulation, no-max softmax, 64-key rounds, double-buffered K/V prefetch.
// grid (96, 8): x = b*12+h (pair pinned to XCD x%8 -> K/V L2-local), y = q-tile.
// block = 256 thr (4 waves); 128 q-rows (32/wave in 2 groups of 16).
// Each round: issue async stage of round k+1 into the other LDS buffer right
// after the barrier, then compute round k -> the end-of-round barrier's
// vmcnt(0) drain waits on loads that have had a full compute phase to land.
__global__ __launch_bounds__(256, 3) void attn_fused(
    const unsigned short* __restrict__ qkvb,  // (3,B,H,N,64) bf16
    const unsigned short* __restrict__ vtb,   // (B,H,64,N) bf16
    const float* __restrict__ maskneg,        // (B,N): 0 keep, -1e9 masked
    unsigned short* __restrict__ attnb) {     // (B,N,H,64) bf16
    const int hb = blockIdx.x, qt = blockIdx.y;
    const int b = hb / Hh, h = hb - b * Hh;
    const int t = threadIdx.x, wv = t >> 6, l = t & 63;
    const int fr = l & 15, quad = l >> 4;
    __shared__ __align__(16) unsigned short Ks[2][64 * 64];
    __shared__ __align__(16) unsigned short VTs[2][64 * 64];
    __shared__ __align__(16) unsigned short Pbuf[4][16 * 72];
    const size_t bh = (size_t)b * Hh + h;
    const unsigned short* Qg = qkvb + bh * (Nn * DHn);
    const unsigned short* Kg = qkvb + (BHn + bh) * (Nn * DHn);
    const unsigned short* Vg = vtb + bh * (DHn * Nn);
    const float* Mg = maskneg + b * Nn;
    const int q0 = qt * 128 + wv * 32;

    // Q fragments for both 16-row groups, pre-scaled by Dh^-0.5 = 0.125 (exact)
    bf16x8 qf[2][2];
#pragma unroll
    for (int g = 0; g < 2; ++g)
#pragma unroll
        for (int c = 0; c < 2; ++c) {
            bf16x8 raw = *(const bf16x8*)&Qg[(size_t)(q0 + g * 16 + fr) * DHn + c * 32 + quad * 8];
            bf16x8 sc;
#pragma unroll
            for (int j = 0; j < 8; ++j)
                sc[j] = (short)f2bf(bf2f((unsigned short)raw[j]) * 0.125f);
            qf[g][c] = sc;
        }
    const f32x4 zero = {0.f, 0.f, 0.f, 0.f};
    f32x4 o[2][4];
    float rs[2] = {0.f, 0.f};
#pragma unroll
    for (int g = 0; g < 2; ++g)
#pragma unroll
        for (int r = 0; r < 4; ++r) o[g][r] = zero;

    const int srow = wv * 8 + (l >> 3);                       // 0..31
    const int lincol = (l & 7) * 8;                           // linear dest chunk
    const int swzcol = (((l & 7) ^ (srow & 7)) << 3);         // swizzled source chunk

    auto stage = [&](int kbase, int bsel) {
        glds16(&Kg[(size_t)(kbase + srow) * DHn + swzcol], &Ks[bsel][srow * 64 + lincol]);
        glds16(&Kg[(size_t)(kbase + srow + 32) * DHn + swzcol], &Ks[bsel][(srow + 32) * 64 + lincol]);
        glds16(&Vg[(size_t)srow * Nn + kbase + swzcol], &VTs[bsel][srow * 64 + lincol]);
        glds16(&Vg[(size_t)(srow + 32) * Nn + kbase + swzcol], &VTs[bsel][(srow + 32) * 64 + lincol]);
    };
    auto loadci = [&](int kbase, f32x4* ci) {
#pragma unroll
        for (int kt = 0; kt < 4; ++kt)
            ci[kt] = *(const f32x4*)&Mg[kbase + kt * 16 + quad * 4];
    };
    auto compute = [&](int bsel, const f32x4* ci) {
        // K fragments once, shared by both q-groups
        bf16x8 kf0[4], kf1[4];
#pragma unroll
        for (int kt = 0; kt < 4; ++kt) {
            int rr = kt * 16 + fr, sw = rr & 7;
            kf0[kt] = *(const bf16x8*)&Ks[bsel][rr * 64 + ((quad ^ sw) << 3)];
            kf1[kt] = *(const bf16x8*)&Ks[bsel][rr * 64 + (((quad + 4) ^ sw) << 3)];
        }
        // S^T = K·Q^T + maskneg : row = key (quad*4+r), col = q (fr)
        f32x4 sg[2][4];
#pragma unroll
        for (int g = 0; g < 2; ++g)
#pragma unroll
            for (int kt = 0; kt < 4; ++kt) {
                f32x4 s = __builtin_amdgcn_mfma_f32_16x16x32_bf16(kf0[kt], qf[g][0], ci[kt], 0, 0, 0);
                sg[g][kt] = __builtin_amdgcn_mfma_f32_16x16x32_bf16(kf1[kt], qf[g][1], s, 0, 0, 0);
            }
        // V fragments once, shared by both q-groups
        bf16x8 vf0[4], vf1[4];
#pragma unroll
        for (int dt = 0; dt < 4; ++dt) {
            int rr = dt * 16 + fr, sw = rr & 7;
            vf0[dt] = *(const bf16x8*)&VTs[bsel][rr * 64 + ((quad ^ sw) << 3)];
            vf1[dt] = *(const bf16x8*)&VTs[bsel][rr * 64 + (((quad + 4) ^ sw) << 3)];
        }
        unsigned short* Pw = Pbuf[wv];
#pragma unroll
        for (int g = 0; g < 2; ++g) {
            // p = exp(s) (masked -> exp(-1e9)=0); per-lane partial sums
#pragma unroll
            for (int kt = 0; kt < 4; ++kt) {
                float p0 = __expf(sg[g][kt][0]);
                float p1 = __expf(sg[g][kt][1]);
                float p2 = __expf(sg[g][kt][2]);
                float p3 = __expf(sg[g][kt][3]);
                rs[g] += (p0 + p1) + (p2 + p3);
                uint2 pk;
                pk.x = pack2bf(p0, p1);
                pk.y = pack2bf(p2, p3);
                // P[q=fr][key=kt*16+quad*4 .. +3]  (b64)
                *(uint2*)&Pw[fr * 72 + kt * 16 + quad * 4] = pk;
            }
            // read back as A-operand (m=q=fr, k=quad*8+j) — b128
            bf16x8 pa0 = *(const bf16x8*)&Pw[fr * 72 + quad * 8];
            bf16x8 pa1 = *(const bf16x8*)&Pw[fr * 72 + 32 + quad * 8];
#pragma unroll
            for (int dt = 0; dt < 4; ++dt) {
                f32x4 t0 = __builtin_amdgcn_mfma_f32_16x16x32_bf16(pa0, vf0[dt], o[g][dt], 0, 0, 0);
                o[g][dt] = __builtin_amdgcn_mfma_f32_16x16x32_bf16(pa1, vf1[dt], t0, 0, 0, 0);
            }
        }
    };

    // prologue: stage round 0 into buffer 0
    f32x4 ciA[4], ciB[4];
    stage(0, 0);
    loadci(0, ciA);
    __syncthreads();
    for (int k0 = 0; k0 < Nn; k0 += 128) {
        // round A: prefetch k0+64 -> buf1, compute k0 from buf0
        stage(k0 + 64, 1);
        loadci(k0 + 64, ciB);
        compute(0, ciA);
        __syncthreads();   // drains prefetch (overlapped by compute above)
        // round B: prefetch k0+128 -> buf0, compute k0+64 from buf1
        if (k0 + 128 < Nn) {
            stage(k0 + 128, 0);
            loadci(k0 + 128, ciA);
        }
        compute(1, ciB);
        __syncthreads();
    }
    // epilogue: finish row sums (across quads), normalize, store
#pragma unroll
    for (int g = 0; g < 2; ++g) {
        float r2 = rs[g] + __shfl_xor(rs[g], 16, 64);
        float rfull = r2 + __shfl_xor(r2, 32, 64);   // valid for q = fr on all lanes
        float inv[4];
#pragma unroll
        for (int r = 0; r < 4; ++r) {
            float lv = __shfl(rfull, quad * 4 + r, 64);   // sum for q = quad*4+r
            inv[r] = (lv > 0.f) ? 1.0f / lv : 0.f;
        }
#pragma unroll
        for (int dt = 0; dt < 4; ++dt)
#pragma unroll
            for (int r = 0; r < 4; ++r) {
                int q = q0 + g * 16 + quad * 4 + r;
                attnb[((size_t)(b * Nn + q) * Hh + h) * DHn + dt * 16 + fr] = f2bf(o[g][dt][r] * inv[r]);
            }
    }
}

// ---------------- workspace layout (bytes, all 256-aligned) ----------------
#define OFF_XB     0u            // 8192*768*2   = 12,582,912
#define OFF_WQKVT  12582912u     // 2304*768*2   =  3,538,944
#define OFF_WPROJT 16121856u     // 768*768*2    =  1,179,648
#define OFF_MASKB  17301504u     // 8192*4       =     32,768
#define OFF_QKVB   17334272u     // 3*96*1024*64*2 = 37,748,736
#define OFF_VTB    55083008u     // 96*64*1024*2 = 12,582,912
#define OFF_ATTNB  67665920u     // 8192*768*2   = 12,582,912
// total 80,248,832 bytes

extern "C" void kernel_launch(void* const* d_in, const int* in_sizes, int n_in,
                              void* d_out, int out_size, void* d_ws, size_t ws_size,
                              hipStream_t stream) {
    const float* x      = (const float*)d_in[0];
    const int*   mask   = (const int*)d_in[1];
    const float* w_qkv  = (const float*)d_in[2];
    const float* w_proj = (const float*)d_in[3];
    const float* b_proj = (const float*)d_in[4];
    float* out = (float*)d_out;
    char* ws = (char*)d_ws;
    unsigned short* xb     = (unsigned short*)(ws + OFF_XB);
    unsigned short* wqkvT  = (unsigned short*)(ws + OFF_WQKVT);
    unsigned short* wprojT = (unsigned short*)(ws + OFF_WPROJT);
    float*          maskng = (float*)(ws + OFF_MASKB);
    unsigned short* qkvb   = (unsigned short*)(ws + OFF_QKVB);
    unsigned short* vtb    = (unsigned short*)(ws + OFF_VTB);
    unsigned short* attnb  = (unsigned short*)(ws + OFF_ATTNB);

    // prep (x-convert + mask fused; both weight transposes in one launch)
    convert_x_mask_kernel<<<dim3(3072), dim3(256), 0, stream>>>(x, xb, mask, maskng, Mrows * Ccn / 8);
    transpose_w2_kernel<<<dim3(96, 24), dim3(32, 8), 0, stream>>>(w_qkv, wqkvT, w_proj, wprojT);
    // qkv = x @ w_qkv  (scattered to (s,b,h,n,d) bf16)
    gemm_qkv_kernel<<<dim3(Mrows / 128, N3C / 128), dim3(256), 0, stream>>>(xb, wqkvT, qkvb);
    // V -> V^T per (b,h)
    transpose_v_kernel<<<dim3(DHn / 32, Nn / 32, BHn), dim3(32, 8), 0, stream>>>(
        qkvb + (size_t)2 * BHn * Nn * DHn, vtb);
    // fused masked flash attention: grid (pairs, q-tiles) for XCD L2 locality
    attn_fused<<<dim3(BHn, Nn / 128), dim3(256), 0, stream>>>(qkvb, vtb, maskng, attnb);
    // out = attn @ w_proj + b
    gemm_proj_kernel<<<dim3(Mrows / 128, Ccn / 64), dim3(256), 0, stream>>>(attnb, wprojT, b_proj, out);
}

// Round 7
// 192.384 us; speedup vs baseline: 1.1095x; 1.1095x over previous
//
#include <hip/hip_runtime.h>
#include <cstdint>
#include <cstddef>

// ---------------- problem constants ----------------
#define Bb   8
#define Nn   1024
#define Ccn  768
#define Hh   12
#define DHn  64
#define Mrows (Bb * Nn)   // 8192
#define N3C  (3 * Ccn)    // 2304
#define BHn  (Bb * Hh)    // 96

typedef __attribute__((ext_vector_type(8))) short bf16x8;   // 8 bf16 (4 VGPRs)
typedef __attribute__((ext_vector_type(4))) float f32x4;

static __device__ __forceinline__ unsigned short f2bf(float f) {
    unsigned int u = __builtin_bit_cast(unsigned int, f);
    return (unsigned short)((u + 0x7FFFu + ((u >> 16) & 1u)) >> 16);  // RNE
}
static __device__ __forceinline__ float bf2f(unsigned short s) {
    unsigned int u = ((unsigned int)s) << 16;
    return __builtin_bit_cast(float, u);
}
// pack two f32 -> two bf16 (round half-up; inputs are finite non-negative p's)
static __device__ __forceinline__ unsigned pack2bf(float a, float b) {
    unsigned ua = __builtin_bit_cast(unsigned, a) + 0x8000u;
    unsigned ub = __builtin_bit_cast(unsigned, b) + 0x8000u;
    return (ua >> 16) | (ub & 0xFFFF0000u);
}
// async global->LDS, 16B per lane; LDS dest must be (wave-uniform base + lane*16)
static __device__ __forceinline__ void glds16(const void* g, void* l) {
    __builtin_amdgcn_global_load_lds((const __attribute__((address_space(1))) void*)g,
                                     (__attribute__((address_space(3))) void*)l,
                                     16, 0, 0);
}

// ---------------- prep kernels ----------------
// x fp32 -> bf16 (vectorized) + mask int -> additive bias (0 / -1e9), fused
__global__ void convert_x_mask_kernel(const float* __restrict__ x,
                                      unsigned short* __restrict__ xb,
                                      const int* __restrict__ mask,
                                      float* __restrict__ maskneg, int n8) {
    int i = blockIdx.x * blockDim.x + threadIdx.x;
    if (i < Mrows) maskneg[i] = (mask[i] != 0) ? -1.0e9f : 0.0f;
    if (i >= n8) return;
    const f32x4* xp = (const f32x4*)x;
    f32x4 a = xp[2 * i], b = xp[2 * i + 1];
    bf16x8 v;
#pragma unroll
    for (int j = 0; j < 4; ++j) {
        v[j]     = (short)f2bf(a[j]);
        v[4 + j] = (short)f2bf(b[j]);
    }
    ((bf16x8*)xb)[i] = v;
}

// both weight transposes in one launch: blockIdx.x<72 -> w_qkv, else w_proj
__global__ void transpose_w2_kernel(const float* __restrict__ Wqkv,
                                    unsigned short* __restrict__ WqkvT,
                                    const float* __restrict__ Wproj,
                                    unsigned short* __restrict__ WprojT) {
    __shared__ float tile[32][33];
    int xb = blockIdx.x;
    const float* W; unsigned short* WT; int C;
    if (xb < 72) { W = Wqkv;  WT = WqkvT;  C = N3C; }
    else         { W = Wproj; WT = WprojT; C = Ccn; xb -= 72; }
    const int R = Ccn;
    const int c0 = xb * 32, r0 = blockIdx.y * 32;
    const int tx = threadIdx.x, ty = threadIdx.y;
#pragma unroll
    for (int i = 0; i < 4; ++i)
        tile[ty + i * 8][tx] = W[(size_t)(r0 + ty + i * 8) * C + c0 + tx];
    __syncthreads();
#pragma unroll
    for (int i = 0; i < 4; ++i)
        WT[(size_t)(c0 + ty + i * 8) * R + r0 + tx] = f2bf(tile[tx][ty + i * 8]);
}

// per (b,h): V (1024 x 64) bf16 -> VT (64 x 1024) bf16
__global__ void transpose_v_kernel(const unsigned short* __restrict__ vb,
                                   unsigned short* __restrict__ vtb) {
    __shared__ unsigned short tile[32][34];
    const int bh = blockIdx.z;
    const int d0 = blockIdx.x * 32, n0 = blockIdx.y * 32;
    const int tx = threadIdx.x, ty = threadIdx.y;
    const unsigned short* src = vb + (size_t)bh * Nn * DHn;
    unsigned short* dst = vtb + (size_t)bh * DHn * Nn;
#pragma unroll
    for (int i = 0; i < 4; ++i)
        tile[ty + i * 8][tx] = src[(size_t)(n0 + ty + i * 8) * DHn + d0 + tx];
    __syncthreads();
#pragma unroll
    for (int i = 0; i < 4; ++i)
        dst[(size_t)(d0 + ty + i * 8) * Nn + n0 + tx] = tile[tx][ty + i * 8];
}

// ---------------- m97-style bf16 GEMM, 128x128 tile, BK=32, swizzled LDS ----
__global__ __launch_bounds__(256) void gemm_qkv_kernel(
    const unsigned short* __restrict__ A,
    const unsigned short* __restrict__ BT,
    unsigned short* __restrict__ qkvb) {
    constexpr int K = Ccn;
    const int bm = blockIdx.x, bn = blockIdx.y;
    const int t = threadIdx.x, wv = t >> 6, l = t & 63;
    const int fr = l & 15, quad = l >> 4;
    const int wm = (wv >> 1) * 64, wn = (wv & 1) * 64;
    __shared__ __align__(16) unsigned short As[128 * 32];
    __shared__ __align__(16) unsigned short Bs[128 * 32];
    const f32x4 zero = {0.f, 0.f, 0.f, 0.f};
    f32x4 acc[4][4];
#pragma unroll
    for (int i = 0; i < 4; ++i)
#pragma unroll
        for (int j = 0; j < 4; ++j) acc[i][j] = zero;

    const int srow = wv * 16 + (l >> 2);                        // 0..63
    const int scol_dst = (l & 3) * 8;                           // linear dest chunk
    const int scol_src = (((l & 3) ^ ((srow >> 1) & 3)) << 3);  // swizzled source chunk
    const unsigned short* Ag = A + (size_t)(bm * 128 + srow) * K + scol_src;
    const unsigned short* Bg = BT + (size_t)(bn * 128 + srow) * K + scol_src;
    unsigned short* Al = &As[srow * 32 + scol_dst];
    unsigned short* Bl = &Bs[srow * 32 + scol_dst];
    const int rsw = ((fr >> 1) & 3);                            // read-side swizzle

    for (int k0 = 0; k0 < K; k0 += 32) {
        glds16(Ag, Al);
        glds16(Ag + (size_t)64 * K, Al + 64 * 32);
        glds16(Bg, Bl);
        glds16(Bg + (size_t)64 * K, Bl + 64 * 32);
        Ag += 32; Bg += 32;
        __syncthreads();
        bf16x8 af[4], bfv[4];
#pragma unroll
        for (int i = 0; i < 4; ++i)
            af[i] = *(const bf16x8*)&As[(wm + i * 16 + fr) * 32 + ((quad ^ rsw) << 3)];
#pragma unroll
        for (int i = 0; i < 4; ++i)
            bfv[i] = *(const bf16x8*)&Bs[(wn + i * 16 + fr) * 32 + ((quad ^ rsw) << 3)];
#pragma unroll
        for (int i = 0; i < 4; ++i)
#pragma unroll
            for (int j = 0; j < 4; ++j)
                acc[i][j] = __builtin_amdgcn_mfma_f32_16x16x32_bf16(af[i], bfv[j], acc[i][j], 0, 0, 0);
        __syncthreads();
    }
    // epilogue: C row = bm*128+wm+i*16+quad*4+r ; col = bn*128+wn+j*16+fr -> (s,h,d)
#pragma unroll
    for (int j = 0; j < 4; ++j) {
        int col = bn * 128 + wn + j * 16 + fr;
        int s = col / Ccn;
        int rem = col - s * Ccn;
        int hh = rem >> 6, d = rem & 63;
#pragma unroll
        for (int i = 0; i < 4; ++i) {
#pragma unroll
            for (int r = 0; r < 4; ++r) {
                int row = bm * 128 + wm + i * 16 + quad * 4 + r;
                int b = row >> 10, nq = row & 1023;
                qkvb[((((size_t)s * Bb + b) * Hh + hh) * Nn + nq) * DHn + d] = f2bf(acc[i][j][r]);
            }
        }
    }
}

// 128x64 tile (N=768 -> 12 col-blocks, grid 768 = 3 blocks/CU balance)
__global__ __launch_bounds__(256) void gemm_proj_kernel(
    const unsigned short* __restrict__ A,   // attnb 8192 x 768
    const unsigned short* __restrict__ BT,  // wprojT 768 x 768
    const float* __restrict__ bias,
    float* __restrict__ out) {
    constexpr int K = Ccn;
    const int bm = blockIdx.x, bn = blockIdx.y;
    const int t = threadIdx.x, wv = t >> 6, l = t & 63;
    const int fr = l & 15, quad = l >> 4;
    const int wm = (wv >> 1) * 64, wn = (wv & 1) * 32;
    __shared__ __align__(16) unsigned short As[128 * 32];
    __shared__ __align__(16) unsigned short Bs[64 * 32];
    const f32x4 zero = {0.f, 0.f, 0.f, 0.f};
    f32x4 acc[4][2];
#pragma unroll
    for (int i = 0; i < 4; ++i)
#pragma unroll
        for (int j = 0; j < 2; ++j) acc[i][j] = zero;

    const int srow = wv * 16 + (l >> 2);
    const int scol_dst = (l & 3) * 8;
    const int scol_src = (((l & 3) ^ ((srow >> 1) & 3)) << 3);
    const unsigned short* Ag = A + (size_t)(bm * 128 + srow) * K + scol_src;
    unsigned short* Al = &As[srow * 32 + scol_dst];
    const int rB = t >> 2, cB = t & 3;                         // B tile: 64 rows x 4 chunks
    const int bsrc = ((cB ^ ((rB >> 1) & 3)) << 3);
    const unsigned short* Bg = BT + (size_t)(bn * 64 + rB) * K + bsrc;
    unsigned short* Bl = &Bs[rB * 32 + cB * 8];
    const int rsw = ((fr >> 1) & 3);

    for (int k0 = 0; k0 < K; k0 += 32) {
        glds16(Ag, Al);
        glds16(Ag + (size_t)64 * K, Al + 64 * 32);
        glds16(Bg, Bl);
        Ag += 32; Bg += 32;
        __syncthreads();
        bf16x8 af[4], bfv[2];
#pragma unroll
        for (int i = 0; i < 4; ++i)
            af[i] = *(const bf16x8*)&As[(wm + i * 16 + fr) * 32 + ((quad ^ rsw) << 3)];
#pragma unroll
        for (int j = 0; j < 2; ++j)
            bfv[j] = *(const bf16x8*)&Bs[(wn + j * 16 + fr) * 32 + ((quad ^ rsw) << 3)];
#pragma unroll
        for (int i = 0; i < 4; ++i)
#pragma unroll
            for (int j = 0; j < 2; ++j)
                acc[i][j] = __builtin_amdgcn_mfma_f32_16x16x32_bf16(af[i], bfv[j], acc[i][j], 0, 0, 0);
        __syncthreads();
    }
#pragma unroll
    for (int j = 0; j < 2; ++j) {
        int col = bn * 64 + wn + j * 16 + fr;
        float bv = bias[col];
#pragma unroll
        for (int i = 0; i < 4; ++i) {
#pragma unroll
            for (int r = 0; r < 4; ++r) {
                int row = bm * 128 + wm + i * 16 + quad * 4 + r;
                out[(size_t)row * Ccn + col] = acc[i][j][r] + bv;
            }
        }
    }
}

// ---------------- fused flash attention ---------------------------------------
// S^T formulation, no-max softmax, 64-key rounds, REGISTER-FREE double buffer:
// K/V/mask all staged via global_load_lds (no VGPR data), so the dbuf costs
// only LDS. Compute body keeps R4's register footprint -> no scratch spill
// under __launch_bounds__(256,3). grid (96, 8): x = b*12+h pins each (b,h)
// pair to XCD x%8 (K/V L2-local); y = q-tile.
__global__ __launch_bounds__(256, 3) void attn_fused(
    const unsigned short* __restrict__ qkvb,  // (3,B,H,N,64) bf16
    const unsigned short* __restrict__ vtb,   // (B,H,64,N) bf16
    const float* __restrict__ maskneg,        // (B,N): 0 keep, -1e9 masked
    unsigned short* __restrict__ attnb) {     // (B,N,H,64) bf16
    const int hb = blockIdx.x, qt = blockIdx.y;
    const int b = hb / Hh, h = hb - b * Hh;
    const int t = threadIdx.x, wv = t >> 6, l = t & 63;
    const int fr = l & 15, quad = l >> 4;
    __shared__ __align__(16) unsigned short Ks[2][64 * 64];
    __shared__ __align__(16) unsigned short VTs[2][64 * 64];
    __shared__ __align__(16) float Ms[2][64];
    __shared__ __align__(16) unsigned short Pbuf[4][16 * 72];
    const size_t bh = (size_t)b * Hh + h;
    const unsigned short* Qg = qkvb + bh * (Nn * DHn);
    const unsigned short* Kg = qkvb + (BHn + bh) * (Nn * DHn);
    const unsigned short* Vg = vtb + bh * (DHn * Nn);
    const float* Mg = maskneg + b * Nn;
    const int q0 = qt * 128 + wv * 32;

    // Q fragments for both 16-row groups, pre-scaled by Dh^-0.5 = 0.125 (exact)
    bf16x8 qf[2][2];
#pragma unroll
    for (int g = 0; g < 2; ++g)
#pragma unroll
        for (int c = 0; c < 2; ++c) {
            bf16x8 raw = *(const bf16x8*)&Qg[(size_t)(q0 + g * 16 + fr) * DHn + c * 32 + quad * 8];
            bf16x8 sc;
#pragma unroll
            for (int j = 0; j < 8; ++j)
                sc[j] = (short)f2bf(bf2f((unsigned short)raw[j]) * 0.125f);
            qf[g][c] = sc;
        }
    const f32x4 zero = {0.f, 0.f, 0.f, 0.f};
    f32x4 o[2][4];
    float rs[2] = {0.f, 0.f};
#pragma unroll
    for (int g = 0; g < 2; ++g)
#pragma unroll
        for (int r = 0; r < 4; ++r) o[g][r] = zero;

    const int srow = wv * 8 + (l >> 3);                       // 0..31
    const int lincol = (l & 7) * 8;                           // linear dest chunk
    const int swzcol = (((l & 7) ^ (srow & 7)) << 3);         // swizzled source chunk

    // stage: 4x K/V glds16 per thread + mask row via lanes t<16 (all VGPR-free)
    auto stage = [&](int kbase, int bsel) {
        glds16(&Kg[(size_t)(kbase + srow) * DHn + swzcol], &Ks[bsel][srow * 64 + lincol]);
        glds16(&Kg[(size_t)(kbase + srow + 32) * DHn + swzcol], &Ks[bsel][(srow + 32) * 64 + lincol]);
        glds16(&Vg[(size_t)srow * Nn + kbase + swzcol], &VTs[bsel][srow * 64 + lincol]);
        glds16(&Vg[(size_t)(srow + 32) * Nn + kbase + swzcol], &VTs[bsel][(srow + 32) * 64 + lincol]);
        if (t < 16) glds16(&Mg[kbase + t * 4], &Ms[bsel][t * 4]);
    };
    auto compute = [&](int bsel) {
        // mask C-init from LDS (broadcast ds_read_b128, 4 per lane)
        f32x4 ci[4];
#pragma unroll
        for (int kt = 0; kt < 4; ++kt)
            ci[kt] = *(const f32x4*)&Ms[bsel][kt * 16 + quad * 4];
        // K fragments once, shared by both q-groups
        bf16x8 kf0[4], kf1[4];
#pragma unroll
        for (int kt = 0; kt < 4; ++kt) {
            int rr = kt * 16 + fr, sw = rr & 7;
            kf0[kt] = *(const bf16x8*)&Ks[bsel][rr * 64 + ((quad ^ sw) << 3)];
            kf1[kt] = *(const bf16x8*)&Ks[bsel][rr * 64 + (((quad + 4) ^ sw) << 3)];
        }
        // S^T = K·Q^T + maskneg : row = key (quad*4+r), col = q (fr)
        f32x4 sg[2][4];
#pragma unroll
        for (int g = 0; g < 2; ++g)
#pragma unroll
            for (int kt = 0; kt < 4; ++kt) {
                f32x4 s = __builtin_amdgcn_mfma_f32_16x16x32_bf16(kf0[kt], qf[g][0], ci[kt], 0, 0, 0);
                sg[g][kt] = __builtin_amdgcn_mfma_f32_16x16x32_bf16(kf1[kt], qf[g][1], s, 0, 0, 0);
            }
        // V fragments once, shared by both q-groups
        bf16x8 vf0[4], vf1[4];
#pragma unroll
        for (int dt = 0; dt < 4; ++dt) {
            int rr = dt * 16 + fr, sw = rr & 7;
            vf0[dt] = *(const bf16x8*)&VTs[bsel][rr * 64 + ((quad ^ sw) << 3)];
            vf1[dt] = *(const bf16x8*)&VTs[bsel][rr * 64 + (((quad + 4) ^ sw) << 3)];
        }
        unsigned short* Pw = Pbuf[wv];
#pragma unroll
        for (int g = 0; g < 2; ++g) {
            // p = exp(s) (masked -> exp(-1e9)=0); per-lane partial sums
#pragma unroll
            for (int kt = 0; kt < 4; ++kt) {
                float p0 = __expf(sg[g][kt][0]);
                float p1 = __expf(sg[g][kt][1]);
                float p2 = __expf(sg[g][kt][2]);
                float p3 = __expf(sg[g][kt][3]);
                rs[g] += (p0 + p1) + (p2 + p3);
                uint2 pk;
                pk.x = pack2bf(p0, p1);
                pk.y = pack2bf(p2, p3);
                // P[q=fr][key=kt*16+quad*4 .. +3]  (b64)
                *(uint2*)&Pw[fr * 72 + kt * 16 + quad * 4] = pk;
            }
            // read back as A-operand (m=q=fr, k=quad*8+j) — b128
            bf16x8 pa0 = *(const bf16x8*)&Pw[fr * 72 + quad * 8];
            bf16x8 pa1 = *(const bf16x8*)&Pw[fr * 72 + 32 + quad * 8];
#pragma unroll
            for (int dt = 0; dt < 4; ++dt) {
                f32x4 t0 = __builtin_amdgcn_mfma_f32_16x16x32_bf16(pa0, vf0[dt], o[g][dt], 0, 0, 0);
                o[g][dt] = __builtin_amdgcn_mfma_f32_16x16x32_bf16(pa1, vf1[dt], t0, 0, 0, 0);
            }
        }
    };

    // prologue: stage round 0 into buffer 0
    stage(0, 0);
    __syncthreads();
    // 16 rounds of 64 keys; stage r+1 (other buffer) right after the barrier,
    // then compute r -> the next barrier's vmcnt(0) drain is fully overlapped.
    for (int r = 0; r < 16; ++r) {
        if (r < 15) stage((r + 1) * 64, (r + 1) & 1);
        compute(r & 1);
        __syncthreads();
    }
    // epilogue: finish row sums (across quads), normalize, store
#pragma unroll
    for (int g = 0; g < 2; ++g) {
        float r2 = rs[g] + __shfl_xor(rs[g], 16, 64);
        float rfull = r2 + __shfl_xor(r2, 32, 64);   // valid for q = fr on all lanes
        float inv[4];
#pragma unroll
        for (int r = 0; r < 4; ++r) {
            float lv = __shfl(rfull, quad * 4 + r, 64);   // sum for q = quad*4+r
            inv[r] = (lv > 0.f) ? 1.0f / lv : 0.f;
        }
#pragma unroll
        for (int dt = 0; dt < 4; ++dt)
#pragma unroll
            for (int r = 0; r < 4; ++r) {
                int q = q0 + g * 16 + quad * 4 + r;
                attnb[((size_t)(b * Nn + q) * Hh + h) * DHn + dt * 16 + fr] = f2bf(o[g][dt][r] * inv[r]);
            }
    }
}

// ---------------- workspace layout (bytes, all 256-aligned) ----------------
#define OFF_XB     0u            // 8192*768*2   = 12,582,912
#define OFF_WQKVT  12582912u     // 2304*768*2   =  3,538,944
#define OFF_WPROJT 16121856u     // 768*768*2    =  1,179,648
#define OFF_MASKB  17301504u     // 8192*4       =     32,768
#define OFF_QKVB   17334272u     // 3*96*1024*64*2 = 37,748,736
#define OFF_VTB    55083008u     // 96*64*1024*2 = 12,582,912
#define OFF_ATTNB  67665920u     // 8192*768*2   = 12,582,912
// total 80,248,832 bytes

extern "C" void kernel_launch(void* const* d_in, const int* in_sizes, int n_in,
                              void* d_out, int out_size, void* d_ws, size_t ws_size,
                              hipStream_t stream) {
    const float* x      = (const float*)d_in[0];
    const int*   mask   = (const int*)d_in[1];
    const float* w_qkv  = (const float*)d_in[2];
    const float* w_proj = (const float*)d_in[3];
    const float* b_proj = (const float*)d_in[4];
    float* out = (float*)d_out;
    char* ws = (char*)d_ws;
    unsigned short* xb     = (unsigned short*)(ws + OFF_XB);
    unsigned short* wqkvT  = (unsigned short*)(ws + OFF_WQKVT);
    unsigned short* wprojT = (unsigned short*)(ws + OFF_WPROJT);
    float*          maskng = (float*)(ws + OFF_MASKB);
    unsigned short* qkvb   = (unsigned short*)(ws + OFF_QKVB);
    unsigned short* vtb    = (unsigned short*)(ws + OFF_VTB);
    unsigned short* attnb  = (unsigned short*)(ws + OFF_ATTNB);

    // prep (x-convert + mask fused; both weight transposes in one launch)
    convert_x_mask_kernel<<<dim3(3072), dim3(256), 0, stream>>>(x, xb, mask, maskng, Mrows * Ccn / 8);
    transpose_w2_kernel<<<dim3(96, 24), dim3(32, 8), 0, stream>>>(w_qkv, wqkvT, w_proj, wprojT);
    // qkv = x @ w_qkv  (scattered to (s,b,h,n,d) bf16)
    gemm_qkv_kernel<<<dim3(Mrows / 128, N3C / 128), dim3(256), 0, stream>>>(xb, wqkvT, qkvb);
    // V -> V^T per (b,h)
    transpose_v_kernel<<<dim3(DHn / 32, Nn / 32, BHn), dim3(32, 8), 0, stream>>>(
        qkvb + (size_t)2 * BHn * Nn * DHn, vtb);
    // fused masked flash attention: grid (pairs, q-tiles) for XCD L2 locality
    attn_fused<<<dim3(BHn, Nn / 128), dim3(256), 0, stream>>>(qkvb, vtb, maskng, attnb);
    // out = attn @ w_proj + b
    gemm_proj_kernel<<<dim3(Mrows / 128, Ccn / 64), dim3(256), 0, stream>>>(attnb, wprojT, b_proj, out);
}